// Round 10
// baseline (1131.223 us; speedup 1.0000x reference)
//
#include <hip/hip_runtime.h>
#include <math.h>

#define Nn 1023
#define NB 256   // persistent grid size

typedef __attribute__((ext_vector_type(8))) short short8;
typedef __attribute__((ext_vector_type(4))) float f32x4;

#define AS1(p) ((const __attribute__((address_space(1))) void*)(p))
#define AS3(p) ((__attribute__((address_space(3))) void*)(p))

__device__ __forceinline__ float sigf(float x) { return 1.0f / (1.0f + __expf(-x)); }
__device__ __forceinline__ float tanhfast(float x) {
    float e = __expf(2.0f * x);
    return 1.0f - 2.0f / (e + 1.0f);
}
__device__ __forceinline__ unsigned short f2bf(float x) {
    unsigned u = __float_as_uint(x);
    return (unsigned short)((u + 0x7fffu + ((u >> 16) & 1u)) >> 16);
}
__device__ __forceinline__ float bf2f(unsigned short b) {
    return __uint_as_float(((unsigned)b) << 16);
}

// Software grid barrier. NB=256 blocks, 64KB dyn LDS -> capacity 2/CU = 512
// slots for 256 blocks: co-residency guaranteed with 2x slack.
__device__ __forceinline__ void gridbar(int* bc, int target) {
    __syncthreads();
    if (threadIdx.x == 0) {
        __threadfence();
        __hip_atomic_fetch_add(bc, 1, __ATOMIC_ACQ_REL, __HIP_MEMORY_SCOPE_AGENT);
        while (__hip_atomic_load(bc, __ATOMIC_ACQUIRE, __HIP_MEMORY_SCOPE_AGENT) < target)
            __builtin_amdgcn_s_sleep(1);
        __threadfence();
    }
    __syncthreads();
}

// ===========================================================================
// prep_all (1825 blocks) — all coalesced pack/transpose, no GEMM work:
//   [0,1024)    pack WhT[P][k2] bf16  (W_hh; P = jhi*64+q*16+jlo)
//   [1024,1536) pack W_iT[P][k] bf16  (W_ih) + w511f[P] fp32
//   [1536,1600) W1 -> W1t
//   [1600,1728) tyv / alphaf / W2t / biasP
//   [1728,1792) A64e = bf16(emb)  (32 x 512)
//   [1792,1825) zero rowidx(8448) + cnt/barrier
// ===========================================================================
__global__ __launch_bounds__(256) void prep_all(
    const float* __restrict__ W_hh, unsigned short* __restrict__ WhT,
    const float* __restrict__ W_ih, unsigned short* __restrict__ W_iT,
    float* __restrict__ w511f,
    const float* __restrict__ W1, float* __restrict__ W1t,
    const int* __restrict__ node_types, const float* __restrict__ node_args,
    const float* __restrict__ emb, const float* __restrict__ W2,
    float* __restrict__ W2t, int* __restrict__ tyv, float* __restrict__ alphaf,
    const float* __restrict__ b_ih, const float* __restrict__ b_hh,
    float* __restrict__ biasP, unsigned short* __restrict__ A64e,
    int* __restrict__ rowidx, int* __restrict__ cnt) {
    int bid = blockIdx.x, t = threadIdx.x;
    if (bid < 1024) {
        int idx = bid * 256 + t;
        int P = idx >> 7;
        int k0 = (idx & 127) * 8;
        int row = ((P >> 4) & 3) * 1024 + (P >> 6) * 16 + (P & 15);
        const float* src = W_hh + (size_t)row * 1024 + k0;
        float4 v0 = *(const float4*)src;
        float4 v1 = *(const float4*)(src + 4);
        short8 o;
        o[0] = (short)f2bf(v0.x); o[1] = (short)f2bf(v0.y);
        o[2] = (short)f2bf(v0.z); o[3] = (short)f2bf(v0.w);
        o[4] = (short)f2bf(v1.x); o[5] = (short)f2bf(v1.y);
        o[6] = (short)f2bf(v1.z); o[7] = (short)f2bf(v1.w);
        *(short8*)(WhT + (size_t)P * 1024 + k0) = o;
    } else if (bid < 1536) {
        int idx = (bid - 1024) * 256 + t;
        int P = idx >> 6;
        int k0 = (idx & 63) * 8;
        int row = ((P >> 4) & 3) * 1024 + (P >> 6) * 16 + (P & 15);
        const float* src = W_ih + (size_t)row * 512 + k0;
        float4 v0 = *(const float4*)src;
        float4 v1 = *(const float4*)(src + 4);
        short8 o;
        o[0] = (short)f2bf(v0.x); o[1] = (short)f2bf(v0.y);
        o[2] = (short)f2bf(v0.z); o[3] = (short)f2bf(v0.w);
        o[4] = (short)f2bf(v1.x); o[5] = (short)f2bf(v1.y);
        o[6] = (short)f2bf(v1.z); o[7] = (short)f2bf(v1.w);
        *(short8*)(W_iT + (size_t)P * 512 + k0) = o;
        if (k0 == 504) w511f[P] = v1.w;
    } else if (bid < 1600) {
        __shared__ float tile[64][65];
        int idx2 = bid - 1536;
        int jb = (idx2 & 7) * 64, kb = (idx2 >> 3) * 64;
        #pragma unroll
        for (int i = 0; i < 16; ++i) {
            int idx = t + i * 256;
            int lj = idx >> 6, lk = idx & 63;
            tile[lj][lk] = W1[(jb + lj) * 512 + kb + lk];
        }
        __syncthreads();
        #pragma unroll
        for (int i = 0; i < 16; ++i) {
            int idx = t + i * 256;
            int lk = idx >> 6, lj = idx & 63;
            W1t[(kb + lk) * 512 + jb + lj] = tile[lj][lk];
        }
    } else if (bid < 1728) {
        int gid = (bid - 1600) * 256 + t;
        if (gid < 32704) {
            int node = gid >> 6, b = gid & 63;
            int ty = node_types[b * Nn + node];
            tyv[gid] = ty;
            alphaf[gid] = (ty <= 1) ? (node_args[b * Nn + node] - emb[ty * 512 + 511]) : 0.f;
        }
        if (gid < 8192) {
            int k = gid >> 4, op = gid & 15;
            W2t[gid] = W2[op * 512 + k];
        }
        if (gid < 2048) {
            int row = ((gid >> 4) & 3) * 1024 + (gid >> 6) * 16 + (gid & 15);
            biasP[gid] = b_ih[row] + b_hh[row];
        }
    } else if (bid < 1792) {
        int o = (bid - 1728) * 256 + t;   // 16384 = 32*512
        A64e[o] = f2bf(emb[o]);
    } else {
        int z = (bid - 1792) * 256 + t;
        if (z < 8448) rowidx[z] = 0;
        if (bid == 1792 && t < 64) cnt[t] = 0;   // cnt[0]=flag count, cnt[32]=barrier
    }
}

__global__ void zero_out(float* __restrict__ outp, int n) {
    int i = blockIdx.x * 256 + threadIdx.x;
    if (i < n) outp[i] = 0.f;
}

// ===========================================================================
// Generic small-M table GEMM via MFMA. NROW=32: C0 only, + biasP at store.
// NROW=64: rows 0-31 -> C0, 32-63 -> C1. B row length = KT*64 bf16.
// ===========================================================================
template<int KT, int NROW>
__device__ __forceinline__ void table_gemm_body(
    char* smemraw, const unsigned short* __restrict__ Abf,
    const unsigned short* __restrict__ Bt, const float* __restrict__ biasP,
    float* __restrict__ C0, float* __restrict__ C1, int by) {
    unsigned short* AB = (unsigned short*)smemraw;
    const int t = threadIdx.x;
    const int w = t >> 6, lane = t & 63;
    const int wr = w >> 1, wc = w & 1;
    const int lane15 = lane & 15, lg = lane >> 4;
    const int bcol0 = by * 128;
    const int lanek8 = (lane & 7) * 8;

    const unsigned short* aA[4];
    const unsigned short* wB[4];
    #pragma unroll
    for (int q = 0; q < 4; ++q) {
        int m = w * 32 + q * 8 + (lane >> 3);
        int r = (m < NROW) ? m : (NROW - 1);
        aA[q] = Abf + (size_t)r * (KT * 64);
        int P = bcol0 + w * 32 + q * 8 + (lane >> 3);
        wB[q] = Bt + (size_t)P * (KT * 64);
    }
    auto stage = [&](int kt, int cur) {
        unsigned short* Ad = AB + cur * 16384;
        unsigned short* Bd = Ad + 8192;
        #pragma unroll
        for (int q = 0; q < 4; ++q) {
            __builtin_amdgcn_global_load_lds(AS1(aA[q] + kt * 64 + lanek8),
                                             AS3(Ad + w * 2048 + q * 512), 16, 0, 0);
            __builtin_amdgcn_global_load_lds(AS1(wB[q] + kt * 64 + lanek8),
                                             AS3(Bd + w * 2048 + q * 512), 16, 0, 0);
        }
    };
    stage(0, 0);
    f32x4 acc[4][4] = {};
    int P4[4];
    #pragma unroll
    for (int q = 0; q < 4; ++q) P4[q] = bcol0 + wc * 64 + q * 16 + lane15;
    int cur = 0;
    for (int kt = 0; kt < KT; ++kt) {
        __syncthreads();
        if (kt < KT - 1) stage(kt + 1, cur ^ 1);
        const unsigned short* Ac = AB + cur * 16384;
        const unsigned short* Bc = Ac + 8192;
        #pragma unroll
        for (int ks = 0; ks < 2; ++ks) {
            short8 av[4], bv[4];
            #pragma unroll
            for (int mi = 0; mi < 4; ++mi)
                av[mi] = *(const short8*)(Ac + (wr * 64 + mi * 16 + lane15) * 64 + ks * 32 + lg * 8);
            #pragma unroll
            for (int q = 0; q < 4; ++q)
                bv[q] = *(const short8*)(Bc + (wc * 64 + q * 16 + lane15) * 64 + ks * 32 + lg * 8);
            #pragma unroll
            for (int mi = 0; mi < 4; ++mi)
                #pragma unroll
                for (int q = 0; q < 4; ++q)
                    acc[mi][q] = __builtin_amdgcn_mfma_f32_16x16x32_bf16(av[mi], bv[q], acc[mi][q], 0, 0, 0);
        }
        cur ^= 1;
    }
    #pragma unroll
    for (int mi = 0; mi < 4; ++mi)
        #pragma unroll
        for (int reg = 0; reg < 4; ++reg) {
            int ro = wr * 64 + mi * 16 + lg * 4 + reg;
            #pragma unroll
            for (int q = 0; q < 4; ++q) {
                float v = acc[mi][q][reg];
                if (NROW == 32) {
                    if (ro < 32) C0[(size_t)ro * 2048 + P4[q]] = v + biasP[P4[q]];
                } else {
                    if (ro < 32) C0[(size_t)ro * 2048 + P4[q]] = v;
                    else if (ro < 64) C1[(size_t)(ro - 32) * 2048 + P4[q]] = v;
                }
            }
        }
    __syncthreads();
}

// ===========================================================================
// ph0: leaf tables + A64 (bid<64), leaf_int (64 rows/block), flag (bid 64..95)
// ===========================================================================
__device__ __forceinline__ void ph0_body(
    int bid,
    const float* __restrict__ E32b, const float* __restrict__ w511f,
    const int* __restrict__ tyv, const float* __restrict__ alphaf,
    unsigned short* __restrict__ Hleaf, float* __restrict__ Cleaf,
    unsigned short* __restrict__ A64,
    unsigned short* __restrict__ Hside, float* __restrict__ Cside,
    int* __restrict__ rowidx, int* __restrict__ cnt) {
    const int t = threadIdx.x;
    if (bid < 64) {
        int o = bid * 256 + t;
        int ty = o >> 9, j = o & 511;
        int Pb = (j >> 4) * 64 + (j & 15);
        const float* Er = E32b + (size_t)ty * 2048;
        float ig = Er[Pb], gg = Er[Pb + 32], og = Er[Pb + 48];
        float cn = sigf(ig) * tanhfast(gg);
        float hn = sigf(og) * tanhfast(cn);
        unsigned short hb = f2bf(hn);
        Hleaf[o] = hb;
        Cleaf[o] = cn;
        A64[ty * 1024 + j] = hb;
        A64[ty * 1024 + 512 + j] = 0;
        A64[(32 + ty) * 1024 + j] = 0;
        A64[(32 + ty) * 1024 + 512 + j] = hb;
    }
    {   // leaf_int: 16384 rows over 256 blocks x 4 waves x 16 rows
        int wave = t >> 6, jc = (t & 63) * 8;
        int r0 = bid * 64 + wave * 16;
        #pragma unroll
        for (int i = 0; i < 16; ++i) {
            int r = r0 + i;
            int gn = 16320 + r;
            int ty = tyv[gn];
            if (ty > 1) continue;
            float al = alphaf[gn];
            int l = r >> 6, b = r & 63;
            const float* Er = E32b + (size_t)ty * 2048;
            short8 hv;
            float cv[8];
            #pragma unroll
            for (int jj = 0; jj < 8; ++jj) {
                int j = jc + jj;
                int Pb = (j >> 4) * 64 + (j & 15);
                float ig = Er[Pb]      + al * w511f[Pb];
                float gg = Er[Pb + 32] + al * w511f[Pb + 32];
                float og = Er[Pb + 48] + al * w511f[Pb + 48];
                float cn = sigf(ig) * tanhfast(gg);
                float hn = sigf(og) * tanhfast(cn);
                hv[jj] = (short)f2bf(hn);
                cv[jj] = cn;
            }
            *(short8*)(Hside + (size_t)r * 512 + jc) = hv;
            if ((l & 1) == 0) {
                size_t cr = ((size_t)((l >> 1) * 64 + b)) * 512 + jc;
                float4 c0 = {cv[0], cv[1], cv[2], cv[3]};
                float4 c1 = {cv[4], cv[5], cv[6], cv[7]};
                *(float4*)(Cside + cr) = c0;
                *(float4*)(Cside + cr + 4) = c1;
            }
        }
    }
    if (bid >= 64 && bid < 96) {
        int r = (bid - 64) * 256 + t;
        int lf = (r >> 6) * 128 + (r & 63);
        if (tyv[16320 + lf] <= 1 || tyv[16320 + lf + 64] <= 1) {
            int p = atomicAdd(cnt, 1);
            rowidx[p] = r;
        }
    }
}

// ===========================================================================
// d=7 table path; SKIPS rows with an int-leaf child (compact MFMA covers them)
// ===========================================================================
__device__ __forceinline__ void d7_table_body(
    char* smemraw,
    const float* __restrict__ E32b, const float* __restrict__ GLt,
    const float* __restrict__ GRt, const float* __restrict__ Cleaf,
    const float* __restrict__ w511f,
    const int* __restrict__ tyv, const float* __restrict__ alphaf,
    unsigned short* __restrict__ out_h, float* __restrict__ out_c,
    int bx, int by) {
    float* Es  = (float*)smemraw;
    float* GLs = Es + 32 * 129;
    float* GRs = GLs + 32 * 129;
    float* Cls = GRs + 32 * 129;
    float* w5s = Cls + 32 * 33;
    const int t = threadIdx.x;
    const int j0 = by * 32;
    const int r = bx * 256 + t;

    for (int i = t; i < 32 * 128; i += 256) {
        int ty = i >> 7, pp = i & 127;
        int gp = ((j0 >> 4) + (pp >> 6)) * 64 + (pp & 63);
        Es[ty * 129 + pp]  = E32b[ty * 2048 + gp];
        GLs[ty * 129 + pp] = GLt[ty * 2048 + gp];
        GRs[ty * 129 + pp] = GRt[ty * 2048 + gp];
    }
    for (int i = t; i < 32 * 32; i += 256) {
        int ty = i >> 5, jl = i & 31;
        Cls[ty * 33 + jl] = Cleaf[ty * 512 + j0 + jl];
    }
    if (t < 128) w5s[t] = w511f[((j0 >> 4) + (t >> 6)) * 64 + (t & 63)];
    __syncthreads();

    int gn = 8128 + r;
    int tyP = tyv[gn];
    float aP = alphaf[gn];
    int lf = (r >> 6) * 128 + (r & 63);
    int tyL = tyv[16320 + lf];
    int tyR = tyv[16320 + lf + 64];
    bool skip = (tyL <= 1) || (tyR <= 1);
    bool evenl = (((r >> 6) & 1) == 0);
    size_t crow = ((size_t)((r >> 7) * 64 + (r & 63))) * 512;

    if (!skip) {
        #pragma unroll
        for (int j8 = 0; j8 < 4; ++j8) {
            short8 hv;
            float cv[8];
            #pragma unroll
            for (int jj = 0; jj < 8; ++jj) {
                int jl = j8 * 8 + jj;
                int ppb = (jl >> 4) * 64 + (jl & 15);
                float ig = Es[tyP * 129 + ppb]      + aP * w5s[ppb]      + GLs[tyL * 129 + ppb]      + GRs[tyR * 129 + ppb];
                float fg = Es[tyP * 129 + ppb + 16] + aP * w5s[ppb + 16] + GLs[tyL * 129 + ppb + 16] + GRs[tyR * 129 + ppb + 16];
                float gg = Es[tyP * 129 + ppb + 32] + aP * w5s[ppb + 32] + GLs[tyL * 129 + ppb + 32] + GRs[tyR * 129 + ppb + 32];
                float og = Es[tyP * 129 + ppb + 48] + aP * w5s[ppb + 48] + GLs[tyL * 129 + ppb + 48] + GRs[tyR * 129 + ppb + 48];
                float cl = Cls[tyL * 33 + jl];
                float cn = sigf(fg) * cl + sigf(ig) * tanhfast(gg);
                float hn = sigf(og) * tanhfast(cn);
                hv[jj] = (short)f2bf(hn);
                cv[jj] = cn;
            }
            *(short8*)(out_h + (size_t)r * 512 + j0 + j8 * 8) = hv;
            if (evenl) {
                float4 c0 = {cv[0], cv[1], cv[2], cv[3]};
                float4 c1 = {cv[4], cv[5], cv[6], cv[7]};
                *(float4*)(out_c + crow + j0 + j8 * 8) = c0;
                *(float4*)(out_c + crow + j0 + j8 * 8 + 4) = c1;
            }
        }
    }
    __syncthreads();
}

// ===========================================================================
// 128x128 level tile. MODE 0: inner level; MODE 2: d=7 compacted rows.
// ===========================================================================
template<int MODE>
__device__ __forceinline__ void mfma_tile(
    char* smemraw,
    const unsigned short* __restrict__ WhT, const float* __restrict__ E32b,
    const float* __restrict__ w511f,
    const int* __restrict__ tyv, const float* __restrict__ alphaf,
    const unsigned short* __restrict__ in_h, const float* __restrict__ in_c,
    const unsigned short* __restrict__ Hleaf, const unsigned short* __restrict__ Hside,
    const float* __restrict__ Cleaf, const float* __restrict__ Cside,
    const int* __restrict__ rowidx, int nc,
    unsigned short* __restrict__ out_h, float* __restrict__ out_c,
    int base, int nloc, int bx, int by) {
    unsigned short* AB = (unsigned short*)smemraw;
    const int t = threadIdx.x;
    const int w = t >> 6, lane = t & 63;
    const int wr = w >> 1, wc = w & 1;
    const int lane15 = lane & 15, lg = lane >> 4;
    const int M = nloc * 64;
    const int brow0 = bx * 128;
    const int bcol0 = by * 128;
    const int lanek8 = (lane & 7) * 8;

    const unsigned short* baseL[4];
    const unsigned short* baseR[4];
    const unsigned short* wB[4];
    #pragma unroll
    for (int q = 0; q < 4; ++q) {
        int m = w * 32 + q * 8 + (lane >> 3);
        int r;
        if (MODE == 2) {
            int idx = brow0 + m; if (idx > nc - 1) idx = nc - 1;
            r = rowidx[idx];
        } else {
            r = brow0 + m; if (r > M - 1) r = M - 1;
        }
        int lf = (r >> 6) * 128 + (r & 63);
        if (MODE == 2) {
            int tyL = tyv[16320 + lf];
            int tyR = tyv[16320 + lf + 64];
            baseL[q] = (tyL <= 1) ? (Hside + (size_t)lf * 512)
                                  : (Hleaf + (size_t)tyL * 512);
            baseR[q] = (tyR <= 1) ? (Hside + (size_t)(lf + 64) * 512)
                                  : (Hleaf + (size_t)tyR * 512);
        } else {
            baseL[q] = in_h + (size_t)lf * 512;
            baseR[q] = baseL[q] + 64 * 512;
        }
        int P = bcol0 + w * 32 + q * 8 + (lane >> 3);
        wB[q] = WhT + (size_t)P * 1024;
    }

    auto stage = [&](int kt, int cur) {
        unsigned short* Ad = AB + cur * 16384;
        unsigned short* Bd = Ad + 8192;
        #pragma unroll
        for (int q = 0; q < 4; ++q) {
            const unsigned short* s = (kt < 8) ? (baseL[q] + kt * 64)
                                               : (baseR[q] + (kt - 8) * 64);
            __builtin_amdgcn_global_load_lds(AS1(s + lanek8),
                                             AS3(Ad + w * 2048 + q * 512), 16, 0, 0);
            __builtin_amdgcn_global_load_lds(AS1(wB[q] + kt * 64 + lanek8),
                                             AS3(Bd + w * 2048 + q * 512), 16, 0, 0);
        }
    };

    stage(0, 0);

    f32x4 acc[4][4];
    float w4[4];
    int P4[4];
    int rr[4][4];
    #pragma unroll
    for (int q = 0; q < 4; ++q) {
        P4[q] = bcol0 + wc * 64 + q * 16 + lane15;
        w4[q] = w511f[P4[q]];
    }
    #pragma unroll
    for (int mi = 0; mi < 4; ++mi) {
        #pragma unroll
        for (int reg = 0; reg < 4; ++reg) {
            int r;
            if (MODE == 2) {
                int idx = brow0 + wr * 64 + mi * 16 + lg * 4 + reg;
                if (idx > nc - 1) idx = nc - 1;
                r = rowidx[idx];
            } else {
                r = brow0 + wr * 64 + mi * 16 + lg * 4 + reg;
                if (r > M - 1) r = M - 1;
            }
            rr[mi][reg] = r;
            int gn = base * 64 + r;
            int ty = tyv[gn];
            float al = alphaf[gn];
            const float* Er = E32b + (size_t)ty * 2048;
            #pragma unroll
            for (int q = 0; q < 4; ++q)
                acc[mi][q][reg] = Er[P4[q]] + al * w4[q];
        }
    }

    int cur = 0;
    for (int kt = 0; kt < 16; ++kt) {
        __syncthreads();
        if (kt < 15) stage(kt + 1, cur ^ 1);
        const unsigned short* Ac = AB + cur * 16384;
        const unsigned short* Bc = Ac + 8192;
        #pragma unroll
        for (int ks = 0; ks < 2; ++ks) {
            short8 av[4], bv[4];
            #pragma unroll
            for (int mi = 0; mi < 4; ++mi)
                av[mi] = *(const short8*)(Ac + (wr * 64 + mi * 16 + lane15) * 64 + ks * 32 + lg * 8);
            #pragma unroll
            for (int q = 0; q < 4; ++q)
                bv[q] = *(const short8*)(Bc + (wc * 64 + q * 16 + lane15) * 64 + ks * 32 + lg * 8);
            #pragma unroll
            for (int mi = 0; mi < 4; ++mi)
                #pragma unroll
                for (int q = 0; q < 4; ++q)
                    acc[mi][q] = __builtin_amdgcn_mfma_f32_16x16x32_bf16(av[mi], bv[q], acc[mi][q], 0, 0, 0);
        }
        cur ^= 1;
    }

    const int j = (by * 2 + wc) * 16 + lane15;
    #pragma unroll
    for (int mi = 0; mi < 4; ++mi) {
        #pragma unroll
        for (int reg = 0; reg < 4; ++reg) {
            int r = rr[mi][reg];
            if (r < M) {
                float ig = acc[mi][0][reg];
                float fg = acc[mi][1][reg];
                float gg = acc[mi][2][reg];
                float og = acc[mi][3][reg];
                float cl;
                if (MODE == 2) {
                    int lf = (r >> 6) * 128 + (r & 63);
                    int tyL = tyv[16320 + lf];
                    cl = (tyL <= 1) ? Cside[(size_t)r * 512 + j]
                                    : Cleaf[(size_t)tyL * 512 + j];
                } else {
                    cl = in_c[(size_t)r * 512 + j];
                }
                float cn = sigf(fg) * cl + sigf(ig) * tanhfast(gg);
                float hn = sigf(og) * tanhfast(cn);
                out_h[(size_t)r * 512 + j] = f2bf(hn);
                if (((r >> 6) & 1) == 0)
                    out_c[((size_t)((r >> 7) * 64 + (r & 63))) * 512 + j] = cn;
            }
        }
    }
}

// ===========================================================================
// Split-K partial GEMM (small levels) + cell reassembly
// ===========================================================================
__device__ __forceinline__ void mfma_split_body(
    char* smemraw, const unsigned short* __restrict__ WhT,
    const unsigned short* __restrict__ in_h, float* __restrict__ Gp,
    int Mrows, int kt0, int nkt, int bx, int by) {
    unsigned short* AB = (unsigned short*)smemraw;
    const int t = threadIdx.x;
    const int w = t >> 6, lane = t & 63;
    const int wr = w >> 1, wc = w & 1;
    const int lane15 = lane & 15, lg = lane >> 4;
    const int brow0 = bx * 128;
    const int bcol0 = by * 128;
    const int lanek8 = (lane & 7) * 8;

    const unsigned short* baseL[4];
    const unsigned short* baseR[4];
    const unsigned short* wB[4];
    #pragma unroll
    for (int q = 0; q < 4; ++q) {
        int m = w * 32 + q * 8 + (lane >> 3);
        int r = brow0 + m; if (r > Mrows - 1) r = Mrows - 1;
        int lf = (r >> 6) * 128 + (r & 63);
        baseL[q] = in_h + (size_t)lf * 512;
        baseR[q] = baseL[q] + 64 * 512;
        int P = bcol0 + w * 32 + q * 8 + (lane >> 3);
        wB[q] = WhT + (size_t)P * 1024;
    }
    auto stage = [&](int kt, int cur) {
        unsigned short* Ad = AB + cur * 16384;
        unsigned short* Bd = Ad + 8192;
        #pragma unroll
        for (int q = 0; q < 4; ++q) {
            const unsigned short* s = (kt < 8) ? (baseL[q] + kt * 64)
                                               : (baseR[q] + (kt - 8) * 64);
            __builtin_amdgcn_global_load_lds(AS1(s + lanek8),
                                             AS3(Ad + w * 2048 + q * 512), 16, 0, 0);
            __builtin_amdgcn_global_load_lds(AS1(wB[q] + kt * 64 + lanek8),
                                             AS3(Bd + w * 2048 + q * 512), 16, 0, 0);
        }
    };
    stage(kt0, 0);
    f32x4 acc[4][4] = {};
    int P4[4];
    int rr[4][4];
    #pragma unroll
    for (int q = 0; q < 4; ++q) P4[q] = bcol0 + wc * 64 + q * 16 + lane15;
    #pragma unroll
    for (int mi = 0; mi < 4; ++mi)
        #pragma unroll
        for (int reg = 0; reg < 4; ++reg) {
            int r = brow0 + wr * 64 + mi * 16 + lg * 4 + reg;
            if (r > Mrows - 1) r = Mrows - 1;
            rr[mi][reg] = r;
        }
    int cur = 0;
    for (int i = 0; i < nkt; ++i) {
        __syncthreads();
        if (i < nkt - 1) stage(kt0 + i + 1, cur ^ 1);
        const unsigned short* Ac = AB + cur * 16384;
        const unsigned short* Bc = Ac + 8192;
        #pragma unroll
        for (int ks = 0; ks < 2; ++ks) {
            short8 av[4], bv[4];
            #pragma unroll
            for (int mi = 0; mi < 4; ++mi)
                av[mi] = *(const short8*)(Ac + (wr * 64 + mi * 16 + lane15) * 64 + ks * 32 + lg * 8);
            #pragma unroll
            for (int q = 0; q < 4; ++q)
                bv[q] = *(const short8*)(Bc + (wc * 64 + q * 16 + lane15) * 64 + ks * 32 + lg * 8);
            #pragma unroll
            for (int mi = 0; mi < 4; ++mi)
                #pragma unroll
                for (int q = 0; q < 4; ++q)
                    acc[mi][q] = __builtin_amdgcn_mfma_f32_16x16x32_bf16(av[mi], bv[q], acc[mi][q], 0, 0, 0);
        }
        cur ^= 1;
    }
    #pragma unroll
    for (int mi = 0; mi < 4; ++mi)
        #pragma unroll
        for (int reg = 0; reg < 4; ++reg) {
            int r = rr[mi][reg];
            #pragma unroll
            for (int q = 0; q < 4; ++q)
                Gp[(size_t)r * 2048 + P4[q]] = acc[mi][q][reg];
        }
    __syncthreads();
}

__device__ __forceinline__ void cell_split_body(
    int bid, const float* __restrict__ Gpart, int KS, int Mrows, int base,
    const float* __restrict__ E32b, const float* __restrict__ w511f,
    const int* __restrict__ tyv, const float* __restrict__ alphaf,
    const float* __restrict__ in_c,
    unsigned short* __restrict__ out_h, float* __restrict__ out_c) {
    int total = Mrows * 64;
    for (int idx = bid * 256 + threadIdx.x; idx < total; idx += NB * 256) {
        int r = idx >> 6;
        int jc = (idx & 63) * 8;
        int gn = base * 64 + r;
        int ty = tyv[gn];
        float al = alphaf[gn];
        const float* Er = E32b + (size_t)ty * 2048;
        short8 hv;
        float cv[8];
        #pragma unroll
        for (int jj = 0; jj < 8; ++jj) {
            int j = jc + jj;
            int Pb = (j >> 4) * 64 + (j & 15);
            float g[4];
            #pragma unroll
            for (int q = 0; q < 4; ++q) {
                int P = Pb + q * 16;
                float s = Er[P] + al * w511f[P];
                for (int ks = 0; ks < KS; ++ks)
                    s += Gpart[((size_t)ks * Mrows + r) * 2048 + P];
                g[q] = s;
            }
            float cl = in_c[(size_t)r * 512 + j];
            float cn = sigf(g[1]) * cl + sigf(g[0]) * tanhfast(g[2]);
            float hn = sigf(g[3]) * tanhfast(cn);
            hv[jj] = (short)f2bf(hn);
            cv[jj] = cn;
        }
        *(short8*)(out_h + (size_t)r * 512 + jc) = hv;
        if (((r >> 6) & 1) == 0) {
            size_t cr = ((size_t)((r >> 7) * 64 + (r & 63))) * 512 + jc;
            float4 c0 = {cv[0], cv[1], cv[2], cv[3]};
            float4 c1 = {cv[4], cv[5], cv[6], cv[7]};
            *(float4*)(out_c + cr) = c0;
            *(float4*)(out_c + cr + 4) = c1;
        }
    }
}

__device__ __forceinline__ void head_body(
    char* smemraw,
    const unsigned short* __restrict__ rootH, const float* __restrict__ W1t,
    const float* __restrict__ b1, const float* __restrict__ W2t,
    const float* __restrict__ b2, const float* __restrict__ vmask,
    float* __restrict__ outp, int b) {
    float* rh = (float*)smemraw;
    float* xs = rh + 512;
    float* part = xs + 512;
    int t = threadIdx.x;
    rh[t] = bf2f(rootH[b * 512 + t]);
    rh[t + 256] = bf2f(rootH[b * 512 + t + 256]);
    __syncthreads();
    #pragma unroll
    for (int jj = 0; jj < 2; ++jj) {
        int jx = t + jj * 256;
        float acc = b1[jx];
        for (int k = 0; k < 512; ++k) acc = fmaf(rh[k], W1t[k * 512 + jx], acc);
        xs[jx] = fmaxf(acc, 0.f);
    }
    __syncthreads();
    int op = t & 15, seg = t >> 4;
    float p = 0.f;
    for (int k = seg * 32; k < seg * 32 + 32; ++k) p = fmaf(xs[k], W2t[k * 16 + op], p);
    part[seg * 17 + op] = p;
    __syncthreads();
    if (t < 16) {
        float s = 0.f;
        #pragma unroll
        for (int g = 0; g < 16; ++g) s += part[g * 17 + t];
        float logit = s + b2[t] + logf(vmask[b * 16 + t]);
        float z = logit * (1.0f / 3.0f);
        float m = z;
        for (int o2 = 8; o2; o2 >>= 1) m = fmaxf(m, __shfl_xor(m, o2, 16));
        float e = __expf(z - m);
        float ssum = e;
        for (int o2 = 8; o2; o2 >>= 1) ssum += __shfl_xor(ssum, o2, 16);
        outp[b * 16 + t] = e / ssum;
    }
}

// ===========================================================================
// Persistent fused kernel. 256 blocks x 256 thr, 64 KB dyn LDS.
// Phases: e32-MFMA -> ph0 -> GLGR -> d7(table+compact) -> d6..d3 ->
// d2/d1/d0 split-K+cell -> head. Software barrier between phases.
// ===========================================================================
__global__ __launch_bounds__(256) void tree_main(
    const unsigned short* WhT, const unsigned short* W_iT,
    const unsigned short* A64e, const float* biasP,
    float* E32b, const float* w511f,
    const int* tyv, const float* alphaf,
    unsigned short* Hleaf, unsigned short* Hside,
    float* Cleaf, float* Cside, unsigned short* A64,
    float* GLt, float* GRt, int* rowidx, int* cnt, float* Gpart,
    unsigned short* Xh, float* Xc, unsigned short* Yh, float* Yc,
    const float* W1t, const float* b1, const float* W2t, const float* b2,
    const float* vmask, float* outp) {
    extern __shared__ char smem[];
    const int bid = blockIdx.x;
    int* bc = cnt + 32;
    int bt = 0;

    // phA: E32b = bf16(emb) @ W_iT + biasP  (16 MFMA tiles)
    if (bid < 16)
        table_gemm_body<8, 32>(smem, A64e, W_iT, biasP, E32b, nullptr, bid);
    bt += NB; gridbar(bc, bt);

    // ph0: leaf tables + A64 + leaf_int + flag
    ph0_body(bid, E32b, w511f, tyv, alphaf, Hleaf, Cleaf, A64, Hside, Cside,
             rowidx, cnt);
    bt += NB; gridbar(bc, bt);

    // ph1: GLGR via MFMA (16 tiles)
    if (bid < 16)
        table_gemm_body<16, 64>(smem, A64, WhT, nullptr, GLt, GRt, bid);
    bt += NB; gridbar(bc, bt);

    // ph2: d=7 table (non-flagged rows; 512 tiles strided) + compact MFMA
    for (int T = bid; T < 512; T += NB)
        d7_table_body(smem, E32b, GLt, GRt, Cleaf, w511f, tyv, alphaf,
                      Xh, Xc, T & 31, T >> 5);
    {
        int nc = __hip_atomic_load(cnt, __ATOMIC_ACQUIRE, __HIP_MEMORY_SCOPE_AGENT);
        int rb = ((nc + 127) & ~127) >> 7;
        for (int T = bid; T < rb * 16; T += NB)
            mfma_tile<2>(smem, WhT, E32b, w511f, tyv, alphaf, nullptr, nullptr,
                         Hleaf, Hside, Cleaf, Cside, rowidx, nc,
                         Xh, Xc, 127, 128, T % rb, T / rb);
    }
    bt += NB; gridbar(bc, bt);

    // d=6..3
    for (int d = 6; d >= 3; --d) {
        int nloc = 1 << d;
        int gx = nloc >> 1;
        unsigned short* oh = (d & 1) ? Xh : Yh;
        float* oc          = (d & 1) ? Xc : Yc;
        const unsigned short* ih = (d & 1) ? Yh : Xh;
        const float* ic          = (d & 1) ? Yc : Xc;
        int ntiles = gx * 16;
        for (int T = bid; T < ntiles; T += NB)
            mfma_tile<0>(smem, WhT, E32b, w511f, tyv, alphaf, ih, ic,
                         nullptr, nullptr, nullptr, nullptr, nullptr, 0,
                         oh, oc, nloc - 1, nloc, T % gx, T / gx);
        bt += NB; gridbar(bc, bt);
    }

    // d=2,1,0: split-K + cell
    {
        const int dv[3]  = {2, 1, 0};
        const int KSv[3] = {4, 8, 8};
        const int kpv[3] = {4, 2, 2};
        const int rtv[3] = {2, 1, 1};
        #pragma unroll
        for (int s = 0; s < 3; ++s) {
            int d = dv[s];
            int nloc = 1 << d;
            int M = nloc * 64;
            int KS = KSv[s], ktpb = kpv[s], rt = rtv[s];
            unsigned short* oh = (d & 1) ? Xh : Yh;
            float* oc          = (d & 1) ? Xc : Yc;
            const unsigned short* ih = (d & 1) ? Yh : Xh;
            const float* ic          = (d & 1) ? Yc : Xc;
            int nblk = rt * 16 * KS;   // <= 128
            if (bid < nblk) {
                int bx = bid % rt;
                int by = (bid / rt) % 16;
                int ks = bid / (rt * 16);
                mfma_split_body(smem, WhT, ih, Gpart + (size_t)ks * M * 2048,
                                M, ks * ktpb, ktpb, bx, by);
            }
            bt += NB; gridbar(bc, bt);
            cell_split_body(bid, Gpart, KS, M, nloc - 1, E32b, w511f, tyv,
                            alphaf, ic, oh, oc);
            bt += NB; gridbar(bc, bt);
        }
    }

    // head (root h in Yh)
    if (bid < 64)
        head_body(smem, Yh, W1t, b1, W2t, b2, vmask, outp, bid);
}

extern "C" void kernel_launch(void* const* d_in, const int* in_sizes, int n_in,
                              void* d_out, int out_size, void* d_ws, size_t ws_size,
                              hipStream_t stream) {
    const int*   node_types = (const int*)d_in[0];
    const float* node_args  = (const float*)d_in[1];
    const float* vmask      = (const float*)d_in[2];
    const float* emb_table  = (const float*)d_in[3];
    const float* W_ih       = (const float*)d_in[4];
    const float* W_hh       = (const float*)d_in[5];
    const float* b_ih       = (const float*)d_in[6];
    const float* b_hh       = (const float*)d_in[7];
    const float* W1         = (const float*)d_in[8];
    const float* b1         = (const float*)d_in[9];
    const float* W2         = (const float*)d_in[10];
    const float* b2         = (const float*)d_in[11];
    float* out = (float*)d_out;

    char* ws = (char*)d_ws;
    size_t off = 0;
    auto alloc = [&](size_t bytes) { char* p = ws + off; off += (bytes + 255) & ~(size_t)255; return p; };
    unsigned short* WhT  = (unsigned short*)alloc((size_t)2048 * 1024 * 2);
    unsigned short* W_iT = (unsigned short*)alloc((size_t)2048 * 512 * 2);
    float* E32b          = (float*)alloc((size_t)32 * 2048 * 4);
    float* w511f         = (float*)alloc(2048 * 4);
    float* biasP         = (float*)alloc(2048 * 4);
    float* W1t           = (float*)alloc((size_t)512 * 512 * 4);
    float* W2t           = (float*)alloc(8192 * 4);
    int*   tyv           = (int*)alloc(32704 * 4);
    float* alphaf        = (float*)alloc(32704 * 4);
    unsigned short* Hleaf= (unsigned short*)alloc((size_t)32 * 512 * 2);
    float* Cleaf         = (float*)alloc((size_t)32 * 512 * 4);
    unsigned short* A64  = (unsigned short*)alloc((size_t)64 * 1024 * 2);
    unsigned short* A64e = (unsigned short*)alloc((size_t)32 * 512 * 2);
    float* GLt           = (float*)alloc((size_t)32 * 2048 * 4);
    float* GRt           = (float*)alloc((size_t)32 * 2048 * 4);
    int*   rowidx        = (int*)alloc(8448 * 4);
    int*   cnt           = (int*)alloc(256);
    float* Gpart         = (float*)alloc((size_t)8 * 256 * 2048 * 4);  // 16 MB
    unsigned short* Hside= (unsigned short*)alloc((size_t)16384 * 512 * 2);
    float* Cside         = (float*)alloc((size_t)8192 * 512 * 4);
    unsigned short* Xh   = (unsigned short*)alloc((size_t)8192 * 512 * 2);
    unsigned short* Yh   = (unsigned short*)alloc((size_t)4096 * 512 * 2);
    float* Xc            = (float*)alloc((size_t)4096 * 512 * 4);
    float* Yc            = (float*)alloc((size_t)2048 * 512 * 4);

    if (ws_size < off) {
        zero_out<<<(out_size + 255) / 256, 256, 0, stream>>>(out, out_size);
        return;
    }

    prep_all<<<1825, 256, 0, stream>>>(
        W_hh, WhT, W_ih, W_iT, w511f, W1, W1t, node_types, node_args,
        emb_table, W2, W2t, tyv, alphaf, b_ih, b_hh, biasP, A64e, rowidx, cnt);

    tree_main<<<NB, 256, 65536, stream>>>(
        WhT, W_iT, A64e, biasP, E32b, w511f, tyv, alphaf,
        Hleaf, Hside, Cleaf, Cside, A64, GLt, GRt, rowidx, cnt, Gpart,
        Xh, Xc, Yh, Yc, W1t, b1, W2t, b2, vmask, out);
}